// Round 1
// baseline (625.799 us; speedup 1.0000x reference)
//
#include <hip/hip_runtime.h>

// Problem constants (fixed by reference)
#define CCH   128      // channels
#define NF    512      // node_feats row = C + 3C
#define OUTF  1408     // 2C + 3*3C
#define HID   64
#define RDIM  8

#define INV_SQRT8  0.35355339059327373f
#define INV_SQRT10 0.31622776601683794f
#define SQRT3      1.7320508075688772f

__device__ __forceinline__ float silu(float x) {
    return x / (1.0f + __expf(-x));
}

// RNE float -> bf16 bits (inputs are finite randn-scale; no NaN handling needed)
__device__ __forceinline__ unsigned int f2bf_bits(float f) {
    unsigned int u = __float_as_uint(f);
    u = (u + 0x7fffu + ((u >> 16) & 1u)) >> 16;
    return u & 0xffffu;
}

// ---------------- CSR build ----------------
__global__ void k_zero(int* __restrict__ counts, int n) {
    int i = blockIdx.x * 256 + threadIdx.x;
    if (i < n) counts[i] = 0;
}

__global__ void k_hist(const int* __restrict__ recv, int* __restrict__ counts, int E) {
    int i = blockIdx.x * 256 + threadIdx.x;
    if (i < E) atomicAdd(&counts[recv[i]], 1);
}

// single-block exclusive scan over n (n=10000), 1024 threads
__global__ void k_scan(const int* __restrict__ counts, int* __restrict__ offsets,
                       int* __restrict__ cursor, int n) {
    __shared__ int sh[1024];
    int t = threadIdx.x;
    int carry = 0;
    for (int base = 0; base < n; base += 1024) {
        int i = base + t;
        int x = (i < n) ? counts[i] : 0;
        sh[t] = x;
        __syncthreads();
        for (int off = 1; off < 1024; off <<= 1) {
            int v = (t >= off) ? sh[t - off] : 0;
            __syncthreads();
            sh[t] += v;
            __syncthreads();
        }
        int incl = sh[t];
        if (i < n) {
            int ex = carry + incl - x;
            offsets[i] = ex;
            cursor[i]  = ex;
        }
        carry += sh[1023];
        __syncthreads();
    }
    if (t == 0) offsets[n] = carry;
}

__global__ void k_perm(const int* __restrict__ recv, int* __restrict__ cursor,
                       int* __restrict__ perm, int E) {
    int i = blockIdx.x * 256 + threadIdx.x;
    if (i < E) {
        int p = atomicAdd(&cursor[recv[i]], 1);
        perm[p] = i;
    }
}

// ---------------- fused main kernel ----------------
// One wave per node. Per lane: channels c = lane, lane+64; mix cols lane+64m (m=0..9).
// w3 staged in LDS as bf16 pairs: entry [mq][k][lane] = (w3[k][lane+128mq], w3[k][lane+64+128mq])
// LDS = 5*64*64*4 B = 81920 B -> exactly 2 blocks/CU.
__global__ __launch_bounds__(256, 2) void k_main(
    const float* __restrict__ vectors,
    const float* __restrict__ node_feats,
    const float* __restrict__ radial,
    const float* __restrict__ w0,
    const float* __restrict__ w1,
    const float* __restrict__ w2,
    const float* __restrict__ w3,
    const int*   __restrict__ senders,
    const int*   __restrict__ offsets,
    const int*   __restrict__ perm,
    float* __restrict__ out, int N)
{
    __shared__ unsigned int w3lds[5 * 64 * 64];

    // stage + convert w3 -> packed bf16 LDS
    for (int idx = threadIdx.x; idx < 5 * 64 * 64; idx += 256) {
        int lane = idx & 63;
        int k    = (idx >> 6) & 63;
        int mq   = idx >> 12;
        int c0 = lane + 128 * mq;
        float a = w3[k * 640 + c0];
        float b = w3[k * 640 + c0 + 64];
        w3lds[idx] = f2bf_bits(a) | (f2bf_bits(b) << 16);
    }
    __syncthreads();

    const int wid  = threadIdx.x >> 6;
    const int lane = threadIdx.x & 63;

    for (int node = blockIdx.x * 4 + wid; node < N; node += gridDim.x * 4) {
        int beg = offsets[node];
        int end = offsets[node + 1];

        float aS[2]     = {0.f, 0.f};
        float aT0[2]    = {0.f, 0.f};
        float aV0[2][3] = {{0.f,0.f,0.f},{0.f,0.f,0.f}};
        float aV1[2][3] = {{0.f,0.f,0.f},{0.f,0.f,0.f}};
        float aV2[2][3] = {{0.f,0.f,0.f},{0.f,0.f,0.f}};

        for (int i0 = beg; i0 < end; i0 += 4) {
            int rem = end - i0;
            int nq = rem < 4 ? rem : 4;

            float h2q[4] = {0.f, 0.f, 0.f, 0.f};
            float rnx[4], rny[4], rnz[4];
            int   snd[4];

            // ---- per-edge MLP (lane j owns h[j]); uniform branch on q<nq ----
            #pragma unroll
            for (int q = 0; q < 4; q++) {
                if (q < nq) {
                    int e = perm[i0 + q];
                    float r8[RDIM];
                    #pragma unroll
                    for (int k = 0; k < RDIM; k++) r8[k] = radial[(size_t)e * RDIM + k];

                    float h = 0.f;
                    #pragma unroll
                    for (int k = 0; k < RDIM; k++) h += r8[k] * w0[k * 64 + lane];
                    h = silu(h * INV_SQRT8);

                    float hn = 0.f;
                    #pragma unroll 8
                    for (int k = 0; k < 64; k++) hn += __shfl(h, k, 64) * w1[k * 64 + lane];
                    h = silu(hn * 0.125f);

                    float hn2 = 0.f;
                    #pragma unroll 8
                    for (int k = 0; k < 64; k++) hn2 += __shfl(h, k, 64) * w2[k * 64 + lane];
                    h2q[q] = silu(hn2 * 0.125f);

                    float vx = vectors[(size_t)e * 3 + 0];
                    float vy = vectors[(size_t)e * 3 + 1];
                    float vz = vectors[(size_t)e * 3 + 2];
                    float inv = rsqrtf(vx * vx + vy * vy + vz * vz);
                    rnx[q] = vx * inv; rny[q] = vy * inv; rnz[q] = vz * inv;
                    snd[q] = senders[e];
                }
            }

            // ---- mix = h2 @ w3, batched over up to 4 edges ----
            float mixv[4][10];
            #pragma unroll
            for (int q = 0; q < 4; q++)
                #pragma unroll
                for (int m = 0; m < 10; m++) mixv[q][m] = 0.f;

            #pragma unroll 4
            for (int k = 0; k < 64; k++) {
                float hq[4];
                #pragma unroll
                for (int q = 0; q < 4; q++) hq[q] = __shfl(h2q[q], k, 64);
                #pragma unroll
                for (int mq = 0; mq < 5; mq++) {
                    unsigned int u = w3lds[(mq * 64 + k) * 64 + lane];
                    float wlo = __uint_as_float(u << 16);
                    float whi = __uint_as_float(u & 0xffff0000u);
                    #pragma unroll
                    for (int q = 0; q < 4; q++) {
                        mixv[q][2 * mq]     += wlo * hq[q];
                        mixv[q][2 * mq + 1] += whi * hq[q];
                    }
                }
            }

            // ---- messages: accumulate into per-lane regs ----
            const float sc = 0.125f * INV_SQRT10;   // w3 scale (1/sqrt(64)) * 1/sqrt(avg_neighbors)
            #pragma unroll
            for (int q = 0; q < 4; q++) {
                if (q < nq) {
                    const float* nf = node_feats + (size_t)snd[q] * NF;
                    #pragma unroll
                    for (int t = 0; t < 2; t++) {
                        int c = lane + 64 * t;
                        float ssv = nf[c];
                        float v0 = nf[CCH + 3 * c + 0];
                        float v1 = nf[CCH + 3 * c + 1];
                        float v2 = nf[CCH + 3 * c + 2];
                        float d = rnx[q] * v0 + rny[q] * v1 + rnz[q] * v2;

                        float m0 = mixv[q][t]     * sc;
                        float m1 = mixv[q][2 + t] * sc;
                        float m2 = mixv[q][4 + t] * sc;
                        float m3 = mixv[q][6 + t] * sc;
                        float m4 = mixv[q][8 + t] * sc * SQRT3;

                        aS[t]  += ssv * m0;
                        aT0[t] += d * m1;
                        aV0[t][0] += v0 * m2;
                        aV0[t][1] += v1 * m2;
                        aV0[t][2] += v2 * m2;
                        aV1[t][0] += ssv * rnx[q] * m3;
                        aV1[t][1] += ssv * rny[q] * m3;
                        aV1[t][2] += ssv * rnz[q] * m3;
                        aV2[t][0] += (d * rnx[q] - v0 * (1.f / 3.f)) * m4;
                        aV2[t][1] += (d * rny[q] - v1 * (1.f / 3.f)) * m4;
                        aV2[t][2] += (d * rnz[q] - v2 * (1.f / 3.f)) * m4;
                    }
                }
            }
        }

        // ---- write this node's 1408 outputs (exactly once, no atomics) ----
        float* ob = out + (size_t)node * OUTF;
        #pragma unroll
        for (int t = 0; t < 2; t++) {
            int c = lane + 64 * t;
            ob[c]           = aS[t];
            ob[CCH + c]     = aT0[t];
            ob[256  + 3 * c + 0] = aV0[t][0];
            ob[256  + 3 * c + 1] = aV0[t][1];
            ob[256  + 3 * c + 2] = aV0[t][2];
            ob[640  + 3 * c + 0] = aV1[t][0];
            ob[640  + 3 * c + 1] = aV1[t][1];
            ob[640  + 3 * c + 2] = aV1[t][2];
            ob[1024 + 3 * c + 0] = aV2[t][0];
            ob[1024 + 3 * c + 1] = aV2[t][1];
            ob[1024 + 3 * c + 2] = aV2[t][2];
        }
    }
}

extern "C" void kernel_launch(void* const* d_in, const int* in_sizes, int n_in,
                              void* d_out, int out_size, void* d_ws, size_t ws_size,
                              hipStream_t stream) {
    const float* vectors    = (const float*)d_in[0];
    const float* node_feats = (const float*)d_in[1];
    const float* radial     = (const float*)d_in[2];
    const float* w0         = (const float*)d_in[3];
    const float* w1         = (const float*)d_in[4];
    const float* w2         = (const float*)d_in[5];
    const float* w3         = (const float*)d_in[6];
    const int*   senders    = (const int*)d_in[7];
    const int*   receivers  = (const int*)d_in[8];

    int E = in_sizes[0] / 3;
    int N = in_sizes[1] / NF;

    // ws layout (ints): counts[N] | offsets[N+1] | cursor[N] | perm[E]  (~520 KB)
    int* counts  = (int*)d_ws;
    int* offsets = counts + N;
    int* cursor  = offsets + N + 1;
    int* perm    = cursor + N;

    k_zero<<<(N + 255) / 256, 256, 0, stream>>>(counts, N);
    k_hist<<<(E + 255) / 256, 256, 0, stream>>>(receivers, counts, E);
    k_scan<<<1, 1024, 0, stream>>>(counts, offsets, cursor, N);
    k_perm<<<(E + 255) / 256, 256, 0, stream>>>(receivers, cursor, perm, E);
    k_main<<<512, 256, 0, stream>>>(vectors, node_feats, radial, w0, w1, w2, w3,
                                    senders, offsets, perm, (float*)d_out, N);
}